// Round 1
// baseline (567.348 us; speedup 1.0000x reference)
//
#include <hip/hip_runtime.h>
#include <stdint.h>

#define LM1  127
#define NTHR 1024

typedef _Float16 half8_t __attribute__((ext_vector_type(8)));
typedef float    f32x4   __attribute__((ext_vector_type(4)));

__device__ __forceinline__ float fast_tanh(float x) {
  float e = __expf(2.0f * x);
  return 1.0f - 2.0f * __builtin_amdgcn_rcpf(e + 1.0f);
}

// LDS-pipe-bound kernel (rocprof: HBM 1%, MFMA 26%, VALU 33%; LDS tally ~80% of
// the 2360 cyc/stage wall). Role split to cut redundant LDS ops:
//   waves 0..7  ("C-waves"): phase-C GEMM2, 4 n-tiles each (f-cols [64w,64w+64)),
//                            kc epilogue, z ownership (lanes 0..31).
//   waves 8..15 ("B-waves"): phase-B GEMM1, 1 n-tile each (wb = w-8).
//   wave 15 lanes 0..31: dXdt staging (gds dbuf) + coeff prefetch.
// Phase-C A-frag reads scale with #C-waves (each wave reads ALL of hA once and
// reuses it across its n-tiles): 16x4 -> 8x4 ds_read_b128 halves the top LDS item.
// kc lane map: lane = cp*32 + hh*4 + r ; handles (row r, h = 8w+hh, c = 4cp+cc).
//   4 in-lane tanh+fma (tanh budget/CU unchanged: 8 waves * 64 lanes * 4 = 2048),
//   ONE shfl_xor(32) combines the two c-quads; owners = lanes 0..31.
__global__ void __launch_bounds__(NTHR, 4) cde_kernel(
    const float* __restrict__ coeffs,
    const float* __restrict__ Wi1, const float* __restrict__ bi1,
    const float* __restrict__ Wi2, const float* __restrict__ bi2,
    const float* __restrict__ W1,  const float* __restrict__ b1,
    const float* __restrict__ W2,  const float* __restrict__ b2,
    float* __restrict__ out)
{
  __shared__ __align__(16) _Float16 zsb[1024];     // 2 KB: chunk = kh*64 + lq*16 + m
  __shared__ __align__(16) _Float16 hA [2048];     // 4 KB: chunk = kt*64 + lq*16 + m
  __shared__ __align__(16) float    fwb[8][288];   // 9 KB: word(cl,r) = 36*(cl>>3)+4*(cl&7)+r, cl 0..63
  __shared__ __align__(16) float    gds[2][3][4][8]; // double-buffered dXdt at fr=0,0.5,1

  const int t    = threadIdx.x;
  const int lane = t & 63;
  const int w    = t >> 6;            // wave 0..15
  const int l15  = lane & 15;
  const int lq   = lane >> 4;
  const int row0 = blockIdx.x * 4;
  const int wc   = w & 7;

  // zero chunk buffers once (rows m>=4 stay zero)
  for (int u = t; u < 512;  u += NTHR) ((uint32_t*)zsb)[u] = 0u;
  for (int u = t; u < 1024; u += NTHR) ((uint32_t*)hA)[u]  = 0u;

  // ---- B-wave weights: W1 -> B-fragments + epilogue constants
  half8_t bB[2] = {};
  float w1t_c = 0.f, b1_c = 0.f;
  _Float16* hwp = &hA[0];
  if (w >= 8) {
    const int wb = w - 8;
    #pragma unroll
    for (int kt = 0; kt < 2; ++kt)
      #pragma unroll
      for (int j = 0; j < 8; ++j)
        bB[kt][j] = (_Float16)W1[(1 + kt * 32 + lq * 8 + j) * 128 + wb * 16 + l15];
    w1t_c = W1[wb * 16 + l15];
    b1_c  = b1[wb * 16 + l15];
    const int col = 16 * wb + l15;    // valid for lanes<16 (writer)
    const int ktw = (col >> 5) & 3, lqw2 = (col >> 3) & 3, j2 = col & 7;
    hwp = &hA[8 * (ktw * 64 + lqw2 * 16) + j2];
  }

  // ---- C-wave weights: W2 -> B-fragments, 4 n-tiles x 4 k-tiles (cols 64w+nt*16+l15)
  half8_t bf[4][4] = {};
  if (w < 8) {
    #pragma unroll
    for (int nt = 0; nt < 4; ++nt)
      #pragma unroll
      for (int kt = 0; kt < 4; ++kt)
        #pragma unroll
        for (int j = 0; j < 8; ++j)
          bf[nt][kt][j] =
              (_Float16)W2[(kt * 32 + lq * 8 + j) * 512 + w * 64 + nt * 16 + l15];
  }

  // ---- kc constants: lane = cp*32 + hh*4 + r, in-lane c = 4cp+cc
  const int r_ = lane & 3;
  const int hh = (lane >> 2) & 7;
  const int cp = lane >> 5;
  float b2c0 = 0.f, b2c1 = 0.f, b2c2 = 0.f, b2c3 = 0.f;
  if (w < 8) {
    const float* bp = b2 + w * 64 + hh * 8 + cp * 4;
    b2c0 = bp[0]; b2c1 = bp[1]; b2c2 = bp[2]; b2c3 = bp[3];
  }
  const int frbase = 36 * hh + 16 * cp + r_;   // fwb word for (cl = 8hh+4cp, row r_)
  const int hx = 8 * wc + hh;                  // owner h-col (lanes<32 of C-waves)

  _Float16* zwp;                               // zsb write slot for this owner
  {
    const int kh = hx >> 5, lqw = (hx >> 3) & 3, jj = hx & 7;
    zwp = &zsb[8 * (kh * 64 + lqw * 16 + r_) + jj];
  }
  float* const fsp = &fwb[wc][36 * (l15 >> 3) + 4 * (l15 & 7)];  // D store base (+72*nt)

  // ---- z0 (owners: C-waves, lanes 0..31)
  float z = 0.0f;
  if (w < 8 && lane < 32) {
    const float* cb = coeffs + (size_t)(row0 + r_) * (LM1 * 32);
    float x0[8];
    #pragma unroll
    for (int c = 0; c < 8; ++c) x0[c] = cb[c];
    float acc = bi2[hx];
    for (int j = 0; j < 20; ++j) {
      float u = bi1[j];
      #pragma unroll
      for (int c = 0; c < 8; ++c) u += x0[c] * Wi1[c * 20 + j];
      acc += fmaxf(u, 0.0f) * Wi2[j * 64 + hx];
    }
    z = fast_tanh(acc);
    out[(size_t)(row0 + r_) * 8192 + hx] = z;
  }

  // ---- coeff prefetch on wave 15 (light B-wave): rg = (lane>>3)&3, cg = lane&7
  const int rg = (lane >> 3) & 3, cg = lane & 7;
  const float* cbp = coeffs + (size_t)(row0 + rg) * (LM1 * 32);
  float pb = 0.f, pc = 0.f, pd = 0.f, pbn = 0.f;
  const bool stg = (w == 15) && (lane < 32);
  if (stg) { pb = cbp[8 + cg]; pc = cbp[16 + cg]; pd = cbp[24 + cg]; pbn = cbp[40 + cg]; }

  __syncthreads();   // init-zero + weight staging complete

  for (int i = 0; i < LM1; ++i) {
    if (stg) {
      gds[i & 1][0][rg][cg] = pb;
      gds[i & 1][1][rg][cg] = pb + pc + 0.75f * pd;
      gds[i & 1][2][rg][cg] = (i < LM1 - 1) ? pbn : fmaf(3.0f, pd, fmaf(2.0f, pc, pb));
      if (i + 1 < LM1) {
        const float* nb = cbp + (size_t)(i + 1) * 32;
        pb = nb[8 + cg]; pc = nb[16 + cg]; pd = nb[24 + cg];
        pbn = (i + 2 < LM1) ? nb[40 + cg] : 0.0f;
      }
    }

    float ksum = 0.0f, kprev = 0.0f;
    #pragma unroll
    for (int s = 0; s < 4; ++s) {
      const float coef = (s == 0) ? 0.0f : (s == 3) ? 1.0f : 0.5f;
      const float ts   = (float)i + ((s == 0) ? 0.0f : (s == 3) ? 1.0f : 0.5f);
      const int   gi   = (s == 0) ? 0 : (s == 3) ? 2 : 1;

      // Phase A: owners stage zs
      if (w < 8 && lane < 32) *zwp = (_Float16)(z + coef * kprev);
      __syncthreads();

      // Phase B (waves 8..15): h-tile wb, reads at 8*lane halfs (conflict-free)
      if (w >= 8) {
        const half8_t a0 = *(const half8_t*)(zsb + 8 * lane);
        const half8_t a1 = *(const half8_t*)(zsb + 512 + 8 * lane);
        f32x4 hd = {0.f, 0.f, 0.f, 0.f};
        hd = __builtin_amdgcn_mfma_f32_16x16x32_f16(a0, bB[0], hd, 0, 0, 0);
        hd = __builtin_amdgcn_mfma_f32_16x16x32_f16(a1, bB[1], hd, 0, 0, 0);
        if (lane < 16) {
          const float hb = fmaf(ts, w1t_c, b1_c);
          hwp[0]  = (_Float16)fmaxf(hd.x + hb, 0.0f);
          hwp[8]  = (_Float16)fmaxf(hd.y + hb, 0.0f);
          hwp[16] = (_Float16)fmaxf(hd.z + hb, 0.0f);
          hwp[24] = (_Float16)fmaxf(hd.w + hb, 0.0f);
        }
      }
      __syncthreads();

      // Phase C (waves 0..7): f-cols [64w, 64w+64), then kc epilogue
      if (w < 8) {
        half8_t ha[4];
        #pragma unroll
        for (int kt = 0; kt < 4; ++kt)
          ha[kt] = *(const half8_t*)(hA + 512 * kt + 8 * lane);
        f32x4 d0 = {0.f, 0.f, 0.f, 0.f}, d1 = d0, d2 = d0, d3 = d0;
        #pragma unroll
        for (int kt = 0; kt < 4; ++kt) {
          d0 = __builtin_amdgcn_mfma_f32_16x16x32_f16(ha[kt], bf[0][kt], d0, 0, 0, 0);
          d1 = __builtin_amdgcn_mfma_f32_16x16x32_f16(ha[kt], bf[1][kt], d1, 0, 0, 0);
          d2 = __builtin_amdgcn_mfma_f32_16x16x32_f16(ha[kt], bf[2][kt], d2, 0, 0, 0);
          d3 = __builtin_amdgcn_mfma_f32_16x16x32_f16(ha[kt], bf[3][kt], d3, 0, 0, 0);
        }
        if (lane < 16) {
          *(f32x4*)(fsp)       = d0;   // cl = l15
          *(f32x4*)(fsp + 72)  = d1;   // cl = 16+l15
          *(f32x4*)(fsp + 144) = d2;   // cl = 32+l15
          *(f32x4*)(fsp + 216) = d3;   // cl = 48+l15
        }
        asm volatile("s_waitcnt lgkmcnt(0)" ::: "memory");  // within-wave handoff

        // kc: 4 in-lane channels, one shfl_xor(32) combines c-quads
        const float* fb = &fwb[wc][frbase];
        const float v0 = fb[0], v1 = fb[4], v2 = fb[8], v3 = fb[12];
        const f32x4 gv = *(const f32x4*)&gds[i & 1][gi][r_][4 * cp];
        float kcv = fast_tanh(v0 + b2c0) * gv.x + fast_tanh(v1 + b2c1) * gv.y
                  + fast_tanh(v2 + b2c2) * gv.z + fast_tanh(v3 + b2c3) * gv.w;
        kcv += __shfl_xor(kcv, 32, 64);
        kprev = kcv;
        ksum += ((s == 1 || s == 2) ? 2.0f : 1.0f) * kcv;
      }
    }
    if (w < 8 && lane < 32) {
      z += ksum * (1.0f / 6.0f);
      out[(size_t)(row0 + r_) * 8192 + (size_t)(i + 1) * 64 + hx] = z;
    }
  }
}

extern "C" void kernel_launch(void* const* d_in, const int* in_sizes, int n_in,
                              void* d_out, int out_size, void* d_ws, size_t ws_size,
                              hipStream_t stream) {
  const float* coeffs = (const float*)d_in[0];
  const float* Wi1    = (const float*)d_in[1];
  const float* bi1    = (const float*)d_in[2];
  const float* Wi2    = (const float*)d_in[3];
  const float* bi2    = (const float*)d_in[4];
  const float* W1     = (const float*)d_in[5];
  const float* b1     = (const float*)d_in[6];
  const float* W2     = (const float*)d_in[7];
  const float* b2     = (const float*)d_in[8];
  float* out          = (float*)d_out;
  (void)in_sizes; (void)n_in; (void)out_size; (void)d_ws; (void)ws_size;
  cde_kernel<<<256, NTHR, 0, stream>>>(coeffs, Wi1, bi1, Wi2, bi2,
                                       W1, b1, W2, b2, out);
}

// Round 2
// 540.251 us; speedup vs baseline: 1.0502x; 1.0502x over previous
//
#include <hip/hip_runtime.h>
#include <stdint.h>

#define LM1  127
#define NTHR 512

typedef _Float16 half8_t __attribute__((ext_vector_type(8)));
typedef float    f32x4   __attribute__((ext_vector_type(4)));

__device__ __forceinline__ float fast_tanh(float x) {
  float e = __expf(2.0f * x);
  return 1.0f - 2.0f * __builtin_amdgcn_rcpf(e + 1.0f);
}

// Latency-bound serial chain (508 RK4 sub-stages x 2 barriers). Round-1 showed
// LDS throughput is NOT binding (halved reads -> slower). This version attacks
// the per-sub-stage critical path:
//   - 8 waves / 512 threads per block: barriers sync half as many waves.
//   - dual-role waves: every wave does phase B (1 h-tile: h-cols [16w,16w+16))
//     AND phase C (4 f-tiles: f-cols [64w,64w+64)) -> no idle-role waves.
//   - gds (dXdt) read hoisted ahead of the phase-C MFMA chain.
//   - kc cross-half combine via v_permlane32_swap_b32 (VALU) instead of
//     __shfl_xor(32) (LDS pipe) -> shorter kc tail.
// kc lane map: lane = cp*32 + hh*4 + r ; handles (row r, h = 8w+hh, c = 4cp+cc),
// 4 in-lane tanh+fma, one permlane swap; owners = lanes 0..31 of each wave.
__global__ void __launch_bounds__(NTHR, 2) cde_kernel(
    const float* __restrict__ coeffs,
    const float* __restrict__ Wi1, const float* __restrict__ bi1,
    const float* __restrict__ Wi2, const float* __restrict__ bi2,
    const float* __restrict__ W1,  const float* __restrict__ b1,
    const float* __restrict__ W2,  const float* __restrict__ b2,
    float* __restrict__ out)
{
  __shared__ __align__(16) _Float16 zsb[1024];       // 2 KB: chunk = kh*64 + lq*16 + m
  __shared__ __align__(16) _Float16 hA [2048];       // 4 KB: chunk = kt*64 + lq*16 + m
  __shared__ __align__(16) float    fwb[8][288];     // 9 KB: word(cl,r) = 36*(cl>>3)+4*(cl&7)+r
  __shared__ __align__(16) float    gds[2][3][4][8]; // double-buffered dXdt at fr=0,0.5,1

  const int t    = threadIdx.x;
  const int lane = t & 63;
  const int w    = t >> 6;            // wave 0..7
  const int l15  = lane & 15;
  const int lq   = lane >> 4;
  const int row0 = blockIdx.x * 4;

  // zero chunk buffers once (rows m>=4 stay zero)
  for (int u = t; u < 512;  u += NTHR) ((uint32_t*)zsb)[u] = 0u;
  for (int u = t; u < 1024; u += NTHR) ((uint32_t*)hA)[u]  = 0u;

  // ---- W1 -> B-fragments (all waves; wave w owns h-cols [16w,16w+16))
  half8_t bB[2];
  #pragma unroll
  for (int kt = 0; kt < 2; ++kt)
    #pragma unroll
    for (int j = 0; j < 8; ++j)
      bB[kt][j] = (_Float16)W1[(1 + kt * 32 + lq * 8 + j) * 128 + w * 16 + l15];
  const float w1t_c = W1[w * 16 + l15];
  const float b1_c  = b1[w * 16 + l15];
  _Float16* hwp;                      // hA write base (phase-B epilogue, lanes<16)
  {
    const int col = 16 * w + l15;
    const int ktw = (col >> 5) & 3, lqw2 = (col >> 3) & 3, j2 = col & 7;
    hwp = &hA[8 * (ktw * 64 + lqw2 * 16) + j2];
  }

  // ---- W2 -> B-fragments: 4 n-tiles x 4 k-tiles (cols 64w + nt*16 + l15)
  half8_t bf[4][4];
  #pragma unroll
  for (int nt = 0; nt < 4; ++nt)
    #pragma unroll
    for (int kt = 0; kt < 4; ++kt)
      #pragma unroll
      for (int j = 0; j < 8; ++j)
        bf[nt][kt][j] =
            (_Float16)W2[(kt * 32 + lq * 8 + j) * 512 + w * 64 + nt * 16 + l15];

  // ---- kc constants: lane = cp*32 + hh*4 + r, in-lane c = 4cp+cc
  const int r_ = lane & 3;
  const int hh = (lane >> 2) & 7;
  const int cp = lane >> 5;
  const float* bp = b2 + w * 64 + hh * 8 + cp * 4;
  const float b2c0 = bp[0], b2c1 = bp[1], b2c2 = bp[2], b2c3 = bp[3];
  const int frbase = 36 * hh + 16 * cp + r_;   // fwb word for (cl = 8hh+4cp, row r_)
  const int hx = 8 * w + hh;                   // owner h-col (lanes 0..31)

  _Float16* zwp;                               // zsb write slot for this owner
  {
    const int kh = hx >> 5, lqw = (hx >> 3) & 3, jj = hx & 7;
    zwp = &zsb[8 * (kh * 64 + lqw * 16 + r_) + jj];
  }
  float* const fsp = &fwb[w][36 * (l15 >> 3) + 4 * (l15 & 7)];  // D store base (+72*nt)

  // ---- z0 (owners: lanes 0..31 of each wave)
  float z = 0.0f;
  if (lane < 32) {
    const float* cb = coeffs + (size_t)(row0 + r_) * (LM1 * 32);
    float x0[8];
    #pragma unroll
    for (int c = 0; c < 8; ++c) x0[c] = cb[c];
    float acc = bi2[hx];
    for (int j = 0; j < 20; ++j) {
      float u = bi1[j];
      #pragma unroll
      for (int c = 0; c < 8; ++c) u += x0[c] * Wi1[c * 20 + j];
      acc += fmaxf(u, 0.0f) * Wi2[j * 64 + hx];
    }
    z = fast_tanh(acc);
    out[(size_t)(row0 + r_) * 8192 + hx] = z;
  }

  // ---- coeff prefetch on wave 7: rg = (lane>>3)&3, cg = lane&7
  const int rg = (lane >> 3) & 3, cg = lane & 7;
  const float* cbp = coeffs + (size_t)(row0 + rg) * (LM1 * 32);
  float pb = 0.f, pc = 0.f, pd = 0.f, pbn = 0.f;
  const bool stg = (w == 7) && (lane < 32);
  if (stg) { pb = cbp[8 + cg]; pc = cbp[16 + cg]; pd = cbp[24 + cg]; pbn = cbp[40 + cg]; }

  __syncthreads();   // init-zero + weight staging complete

  for (int i = 0; i < LM1; ++i) {
    if (stg) {
      gds[i & 1][0][rg][cg] = pb;
      gds[i & 1][1][rg][cg] = pb + pc + 0.75f * pd;
      gds[i & 1][2][rg][cg] = (i < LM1 - 1) ? pbn : fmaf(3.0f, pd, fmaf(2.0f, pc, pb));
      if (i + 1 < LM1) {
        const float* nb = cbp + (size_t)(i + 1) * 32;
        pb = nb[8 + cg]; pc = nb[16 + cg]; pd = nb[24 + cg];
        pbn = (i + 2 < LM1) ? nb[40 + cg] : 0.0f;
      }
    }

    float ksum = 0.0f, kprev = 0.0f;
    #pragma unroll
    for (int s = 0; s < 4; ++s) {
      const float coef = (s == 0) ? 0.0f : (s == 3) ? 1.0f : 0.5f;
      const float ts   = (float)i + ((s == 0) ? 0.0f : (s == 3) ? 1.0f : 0.5f);
      const int   gi   = (s == 0) ? 0 : (s == 3) ? 2 : 1;

      // Phase A: owners stage zs
      if (lane < 32) *zwp = (_Float16)(z + coef * kprev);
      __syncthreads();

      // Phase B (all waves): h-tile w, reads at 8*lane halfs (conflict-free)
      {
        const half8_t a0 = *(const half8_t*)(zsb + 8 * lane);
        const half8_t a1 = *(const half8_t*)(zsb + 512 + 8 * lane);
        f32x4 hd = {0.f, 0.f, 0.f, 0.f};
        hd = __builtin_amdgcn_mfma_f32_16x16x32_f16(a0, bB[0], hd, 0, 0, 0);
        hd = __builtin_amdgcn_mfma_f32_16x16x32_f16(a1, bB[1], hd, 0, 0, 0);
        if (lane < 16) {
          const float hb = fmaf(ts, w1t_c, b1_c);
          hwp[0]  = (_Float16)fmaxf(hd.x + hb, 0.0f);
          hwp[8]  = (_Float16)fmaxf(hd.y + hb, 0.0f);
          hwp[16] = (_Float16)fmaxf(hd.z + hb, 0.0f);
          hwp[24] = (_Float16)fmaxf(hd.w + hb, 0.0f);
        }
      }
      __syncthreads();

      // Phase C (all waves): f-cols [64w, 64w+64), then kc epilogue
      {
        // hoist the dXdt read: depends only on (i, s), not on the MFMA chain
        const f32x4 gv = *(const f32x4*)&gds[i & 1][gi][r_][4 * cp];

        half8_t ha[4];
        #pragma unroll
        for (int kt = 0; kt < 4; ++kt)
          ha[kt] = *(const half8_t*)(hA + 512 * kt + 8 * lane);
        f32x4 d0 = {0.f, 0.f, 0.f, 0.f}, d1 = d0, d2 = d0, d3 = d0;
        #pragma unroll
        for (int kt = 0; kt < 4; ++kt) {
          d0 = __builtin_amdgcn_mfma_f32_16x16x32_f16(ha[kt], bf[0][kt], d0, 0, 0, 0);
          d1 = __builtin_amdgcn_mfma_f32_16x16x32_f16(ha[kt], bf[1][kt], d1, 0, 0, 0);
          d2 = __builtin_amdgcn_mfma_f32_16x16x32_f16(ha[kt], bf[2][kt], d2, 0, 0, 0);
          d3 = __builtin_amdgcn_mfma_f32_16x16x32_f16(ha[kt], bf[3][kt], d3, 0, 0, 0);
        }
        if (lane < 16) {
          *(f32x4*)(fsp)       = d0;   // cl = l15
          *(f32x4*)(fsp + 72)  = d1;   // cl = 16+l15
          *(f32x4*)(fsp + 144) = d2;   // cl = 32+l15
          *(f32x4*)(fsp + 216) = d3;   // cl = 48+l15
        }
        asm volatile("s_waitcnt lgkmcnt(0)" ::: "memory");  // within-wave handoff

        // kc: 4 in-lane channels; cross-half combine on the VALU pipe
        const float* fb = &fwb[w][frbase];
        const float v0 = fb[0], v1 = fb[4], v2 = fb[8], v3 = fb[12];
        float kcv = fast_tanh(v0 + b2c0) * gv.x + fast_tanh(v1 + b2c1) * gv.y
                  + fast_tanh(v2 + b2c2) * gv.z + fast_tanh(v3 + b2c3) * gv.w;
        {
          int a = __float_as_int(kcv), b = a;
          asm volatile("v_permlane32_swap_b32 %0, %1" : "+v"(a), "+v"(b));
          kcv = __int_as_float(a) + __int_as_float(b);
        }
        kprev = kcv;
        ksum += ((s == 1 || s == 2) ? 2.0f : 1.0f) * kcv;
      }
    }
    if (lane < 32) {
      z += ksum * (1.0f / 6.0f);
      out[(size_t)(row0 + r_) * 8192 + (size_t)(i + 1) * 64 + hx] = z;
    }
  }
}

extern "C" void kernel_launch(void* const* d_in, const int* in_sizes, int n_in,
                              void* d_out, int out_size, void* d_ws, size_t ws_size,
                              hipStream_t stream) {
  const float* coeffs = (const float*)d_in[0];
  const float* Wi1    = (const float*)d_in[1];
  const float* bi1    = (const float*)d_in[2];
  const float* Wi2    = (const float*)d_in[3];
  const float* bi2    = (const float*)d_in[4];
  const float* W1     = (const float*)d_in[5];
  const float* b1     = (const float*)d_in[6];
  const float* W2     = (const float*)d_in[7];
  const float* b2     = (const float*)d_in[8];
  float* out          = (float*)d_out;
  (void)in_sizes; (void)n_in; (void)out_size; (void)d_ws; (void)ws_size;
  cde_kernel<<<256, NTHR, 0, stream>>>(coeffs, Wi1, bi1, Wi2, bi2,
                                       W1, b1, W2, b2, out);
}

// Round 3
// 537.876 us; speedup vs baseline: 1.0548x; 1.0044x over previous
//
#include <hip/hip_runtime.h>
#include <stdint.h>

#define LM1  127
#define NTHR 512

typedef _Float16 half8_t __attribute__((ext_vector_type(8)));
typedef float    f32x4   __attribute__((ext_vector_type(4)));

__device__ __forceinline__ float fast_tanh(float x) {
  float e = __expf(2.0f * x);
  return 1.0f - 2.0f * __builtin_amdgcn_rcpf(e + 1.0f);
}

// Round-3 theory: the invariant ~2100 cyc/sub-stage across rounds 0-2 is the
// __syncthreads() vmcnt(0) drain: every barrier forces each wave to wait for
// its own out[] store-acks and the prefetch wave's global loads, and the whole
// block waits for that straggler. Replace in-loop __syncthreads() with raw
//   s_waitcnt lgkmcnt(0) ; s_barrier      (LDS-visibility-only barrier)
// so global stores stay fire-and-forget and the coeff prefetch stays in
// flight across barriers (its vmcnt wait lands at the next gds write, ~one
// full sub-stage later -> hidden).
// Structure otherwise identical to round 2 (8 waves dual-role).
#define BAR() asm volatile("s_waitcnt lgkmcnt(0)\n\ts_barrier" ::: "memory")

__global__ void __launch_bounds__(NTHR, 2) cde_kernel(
    const float* __restrict__ coeffs,
    const float* __restrict__ Wi1, const float* __restrict__ bi1,
    const float* __restrict__ Wi2, const float* __restrict__ bi2,
    const float* __restrict__ W1,  const float* __restrict__ b1,
    const float* __restrict__ W2,  const float* __restrict__ b2,
    float* __restrict__ out)
{
  __shared__ __align__(16) _Float16 zsb[1024];       // 2 KB: chunk = kh*64 + lq*16 + m
  __shared__ __align__(16) _Float16 hA [2048];       // 4 KB: chunk = kt*64 + lq*16 + m
  __shared__ __align__(16) float    fwb[8][288];     // 9 KB: word(cl,r) = 36*(cl>>3)+4*(cl&7)+r
  __shared__ __align__(16) float    gds[2][3][4][8]; // double-buffered dXdt at fr=0,0.5,1

  const int t    = threadIdx.x;
  const int lane = t & 63;
  const int w    = t >> 6;            // wave 0..7
  const int l15  = lane & 15;
  const int lq   = lane >> 4;
  const int row0 = blockIdx.x * 4;

  // zero chunk buffers once (rows m>=4 stay zero)
  for (int u = t; u < 512;  u += NTHR) ((uint32_t*)zsb)[u] = 0u;
  for (int u = t; u < 1024; u += NTHR) ((uint32_t*)hA)[u]  = 0u;

  // ---- W1 -> B-fragments (all waves; wave w owns h-cols [16w,16w+16))
  half8_t bB[2];
  #pragma unroll
  for (int kt = 0; kt < 2; ++kt)
    #pragma unroll
    for (int j = 0; j < 8; ++j)
      bB[kt][j] = (_Float16)W1[(1 + kt * 32 + lq * 8 + j) * 128 + w * 16 + l15];
  const float w1t_c = W1[w * 16 + l15];
  const float b1_c  = b1[w * 16 + l15];
  _Float16* hwp;                      // hA write base (phase-B epilogue, lanes<16)
  {
    const int col = 16 * w + l15;
    const int ktw = (col >> 5) & 3, lqw2 = (col >> 3) & 3, j2 = col & 7;
    hwp = &hA[8 * (ktw * 64 + lqw2 * 16) + j2];
  }

  // ---- W2 -> B-fragments: 4 n-tiles x 4 k-tiles (cols 64w + nt*16 + l15)
  half8_t bf[4][4];
  #pragma unroll
  for (int nt = 0; nt < 4; ++nt)
    #pragma unroll
    for (int kt = 0; kt < 4; ++kt)
      #pragma unroll
      for (int j = 0; j < 8; ++j)
        bf[nt][kt][j] =
            (_Float16)W2[(kt * 32 + lq * 8 + j) * 512 + w * 64 + nt * 16 + l15];

  // ---- kc constants: lane = cp*32 + hh*4 + r, in-lane c = 4cp+cc
  const int r_ = lane & 3;
  const int hh = (lane >> 2) & 7;
  const int cp = lane >> 5;
  const float* bp = b2 + w * 64 + hh * 8 + cp * 4;
  const float b2c0 = bp[0], b2c1 = bp[1], b2c2 = bp[2], b2c3 = bp[3];
  const int frbase = 36 * hh + 16 * cp + r_;   // fwb word for (cl = 8hh+4cp, row r_)
  const int hx = 8 * w + hh;                   // owner h-col (lanes 0..31)

  _Float16* zwp;                               // zsb write slot for this owner
  {
    const int kh = hx >> 5, lqw = (hx >> 3) & 3, jj = hx & 7;
    zwp = &zsb[8 * (kh * 64 + lqw * 16 + r_) + jj];
  }
  float* const fsp = &fwb[w][36 * (l15 >> 3) + 4 * (l15 & 7)];  // D store base (+72*nt)

  // ---- z0 (owners: lanes 0..31 of each wave)
  float z = 0.0f;
  if (lane < 32) {
    const float* cb = coeffs + (size_t)(row0 + r_) * (LM1 * 32);
    float x0[8];
    #pragma unroll
    for (int c = 0; c < 8; ++c) x0[c] = cb[c];
    float acc = bi2[hx];
    for (int j = 0; j < 20; ++j) {
      float u = bi1[j];
      #pragma unroll
      for (int c = 0; c < 8; ++c) u += x0[c] * Wi1[c * 20 + j];
      acc += fmaxf(u, 0.0f) * Wi2[j * 64 + hx];
    }
    z = fast_tanh(acc);
    out[(size_t)(row0 + r_) * 8192 + hx] = z;
  }

  // ---- coeff prefetch on wave 7: rg = (lane>>3)&3, cg = lane&7
  const int rg = (lane >> 3) & 3, cg = lane & 7;
  const float* cbp = coeffs + (size_t)(row0 + rg) * (LM1 * 32);
  float pb = 0.f, pc = 0.f, pd = 0.f, pbn = 0.f;
  const bool stg = (w == 7) && (lane < 32);
  if (stg) { pb = cbp[8 + cg]; pc = cbp[16 + cg]; pd = cbp[24 + cg]; pbn = cbp[40 + cg]; }

  __syncthreads();   // init-zero + weight staging complete (full barrier, once)

  for (int i = 0; i < LM1; ++i) {
    if (stg) {
      gds[i & 1][0][rg][cg] = pb;
      gds[i & 1][1][rg][cg] = pb + pc + 0.75f * pd;
      gds[i & 1][2][rg][cg] = (i < LM1 - 1) ? pbn : fmaf(3.0f, pd, fmaf(2.0f, pc, pb));
      if (i + 1 < LM1) {
        const float* nb = cbp + (size_t)(i + 1) * 32;
        pb = nb[8 + cg]; pc = nb[16 + cg]; pd = nb[24 + cg];
        pbn = (i + 2 < LM1) ? nb[40 + cg] : 0.0f;
      }
    }

    float ksum = 0.0f, kprev = 0.0f;
    #pragma unroll
    for (int s = 0; s < 4; ++s) {
      const float coef = (s == 0) ? 0.0f : (s == 3) ? 1.0f : 0.5f;
      const float ts   = (float)i + ((s == 0) ? 0.0f : (s == 3) ? 1.0f : 0.5f);
      const int   gi   = (s == 0) ? 0 : (s == 3) ? 2 : 1;

      // Phase A: owners stage zs
      if (lane < 32) *zwp = (_Float16)(z + coef * kprev);
      BAR();   // lgkm-only barrier: zsb (+ gds at s=0) visible; vmem stays in flight

      // Phase B (all waves): h-tile w, reads at 8*lane halfs (conflict-free)
      {
        const half8_t a0 = *(const half8_t*)(zsb + 8 * lane);
        const half8_t a1 = *(const half8_t*)(zsb + 512 + 8 * lane);
        f32x4 hd = {0.f, 0.f, 0.f, 0.f};
        hd = __builtin_amdgcn_mfma_f32_16x16x32_f16(a0, bB[0], hd, 0, 0, 0);
        hd = __builtin_amdgcn_mfma_f32_16x16x32_f16(a1, bB[1], hd, 0, 0, 0);
        if (lane < 16) {
          const float hb = fmaf(ts, w1t_c, b1_c);
          hwp[0]  = (_Float16)fmaxf(hd.x + hb, 0.0f);
          hwp[8]  = (_Float16)fmaxf(hd.y + hb, 0.0f);
          hwp[16] = (_Float16)fmaxf(hd.z + hb, 0.0f);
          hwp[24] = (_Float16)fmaxf(hd.w + hb, 0.0f);
        }
      }
      BAR();   // lgkm-only barrier: hA visible

      // Phase C (all waves): f-cols [64w, 64w+64), then kc epilogue
      {
        // hoist the dXdt read: depends only on (i, s), not on the MFMA chain
        const f32x4 gv = *(const f32x4*)&gds[i & 1][gi][r_][4 * cp];

        half8_t ha[4];
        #pragma unroll
        for (int kt = 0; kt < 4; ++kt)
          ha[kt] = *(const half8_t*)(hA + 512 * kt + 8 * lane);
        f32x4 d0 = {0.f, 0.f, 0.f, 0.f}, d1 = d0, d2 = d0, d3 = d0;
        #pragma unroll
        for (int kt = 0; kt < 4; ++kt) {
          d0 = __builtin_amdgcn_mfma_f32_16x16x32_f16(ha[kt], bf[0][kt], d0, 0, 0, 0);
          d1 = __builtin_amdgcn_mfma_f32_16x16x32_f16(ha[kt], bf[1][kt], d1, 0, 0, 0);
          d2 = __builtin_amdgcn_mfma_f32_16x16x32_f16(ha[kt], bf[2][kt], d2, 0, 0, 0);
          d3 = __builtin_amdgcn_mfma_f32_16x16x32_f16(ha[kt], bf[3][kt], d3, 0, 0, 0);
        }
        if (lane < 16) {
          *(f32x4*)(fsp)       = d0;   // cl = l15
          *(f32x4*)(fsp + 72)  = d1;   // cl = 16+l15
          *(f32x4*)(fsp + 144) = d2;   // cl = 32+l15
          *(f32x4*)(fsp + 216) = d3;   // cl = 48+l15
        }
        asm volatile("s_waitcnt lgkmcnt(0)" ::: "memory");  // within-wave handoff

        // kc: 4 in-lane channels; cross-half combine on the VALU pipe
        const float* fb = &fwb[w][frbase];
        const float v0 = fb[0], v1 = fb[4], v2 = fb[8], v3 = fb[12];
        float kcv = fast_tanh(v0 + b2c0) * gv.x + fast_tanh(v1 + b2c1) * gv.y
                  + fast_tanh(v2 + b2c2) * gv.z + fast_tanh(v3 + b2c3) * gv.w;
        {
          int a = __float_as_int(kcv), b = a;
          asm volatile("v_permlane32_swap_b32 %0, %1" : "+v"(a), "+v"(b));
          kcv = __int_as_float(a) + __int_as_float(b);
        }
        kprev = kcv;
        ksum += ((s == 1 || s == 2) ? 2.0f : 1.0f) * kcv;
      }
    }
    if (lane < 32) {
      z += ksum * (1.0f / 6.0f);
      out[(size_t)(row0 + r_) * 8192 + (size_t)(i + 1) * 64 + hx] = z;  // fire-and-forget
    }
  }
}

extern "C" void kernel_launch(void* const* d_in, const int* in_sizes, int n_in,
                              void* d_out, int out_size, void* d_ws, size_t ws_size,
                              hipStream_t stream) {
  const float* coeffs = (const float*)d_in[0];
  const float* Wi1    = (const float*)d_in[1];
  const float* bi1    = (const float*)d_in[2];
  const float* Wi2    = (const float*)d_in[3];
  const float* bi2    = (const float*)d_in[4];
  const float* W1     = (const float*)d_in[5];
  const float* b1     = (const float*)d_in[6];
  const float* W2     = (const float*)d_in[7];
  const float* b2     = (const float*)d_in[8];
  float* out          = (float*)d_out;
  (void)in_sizes; (void)n_in; (void)out_size; (void)d_ws; (void)ws_size;
  cde_kernel<<<256, NTHR, 0, stream>>>(coeffs, Wi1, bi1, Wi2, bi2,
                                       W1, b1, W2, b2, out);
}